// Round 5
// baseline (468.385 us; speedup 1.0000x reference)
//
#include <hip/hip_runtime.h>
#include <hip/hip_bf16.h>
#include <math.h>

#define N_  8
#define C_  528
#define T_  16
#define H_  32
#define W_  32
#define HW_ 1024
#define R_  1024
#define OUT_ 8
#define SCALE_ (1.0f/16.0f)

// ---------------------------------------------------------------------------
// Kernel 1: feat_t[n][p][c] = mean_t x[n][c][t][p], NCHW -> N(HW)C transpose.
// HBM-bound: 277 MB read + 17 MB write ~ 47 us floor.
// ---------------------------------------------------------------------------
__global__ __launch_bounds__(256) void mean_transpose(
    const float* __restrict__ x, float* __restrict__ feat_t) {
  const int p0 = blockIdx.x * 64;
  const int c0 = blockIdx.y * 64;
  const int n  = blockIdx.z;

  __shared__ float tile[64][68];

  const int tid = threadIdx.x;
  const int p4  = (tid & 15) * 4;
  const int clo = tid >> 4;

  const float inv_t = 1.0f / 16.0f;
  #pragma unroll
  for (int k = 0; k < 4; ++k) {
    const int c_local = clo + 16 * k;
    const int c = c0 + c_local;
    float4 acc = make_float4(0.f, 0.f, 0.f, 0.f);
    if (c < C_) {
      const float* src = x + ((size_t)(n * C_ + c) * T_) * HW_ + p0 + p4;
      #pragma unroll
      for (int t = 0; t < T_; ++t) {
        const float4 v = *(const float4*)(src + t * HW_);
        acc.x += v.x; acc.y += v.y; acc.z += v.z; acc.w += v.w;
      }
    }
    tile[p4 + 0][c_local] = acc.x * inv_t;
    tile[p4 + 1][c_local] = acc.y * inv_t;
    tile[p4 + 2][c_local] = acc.z * inv_t;
    tile[p4 + 3][c_local] = acc.w * inv_t;
  }
  __syncthreads();

  const int c4 = (tid & 15) * 4;
  const int p  = tid >> 4;
  if (c0 + c4 < C_) {
    #pragma unroll
    for (int k = 0; k < 4; ++k) {
      const int p_out = p + 16 * k;
      const float4 v = *(const float4*)&tile[p_out][c4];
      *(float4*)&feat_t[((size_t)n * HW_ + p0 + p_out) * C_ + c0 + c4] = v;
    }
  }
}

// ---------------------------------------------------------------------------
// Kernel 2: per-roi separable ROI-align + spatial mean -> pooled[r][528].
// (Y-row, channel-quad) tasks; fixed 9-tap UNROLLED X gather (zero-padded
// weights) so all 9 loads are independent/in-flight. grid=1024, block=256.
// ---------------------------------------------------------------------------
__global__ __launch_bounds__(256) void roi_pool(
    const float* __restrict__ feat_t, const float* __restrict__ bbox,
    float* __restrict__ pooled_g) {
  const int r = blockIdx.x;
  const int tid = threadIdx.x;

  __shared__ float sAy[40], sAx[40];              // zero-padded supports
  __shared__ __align__(16) float pooledP[9][C_];  // per-Y partials (19 KB)
  __shared__ int sb[3];                           // ylo, xlo, bidx

  if (tid < 40) sAy[tid] = 0.f;
  else if (tid < 80) sAx[tid - 40] = 0.f;
  __syncthreads();

  // --- Phase A: separable weights + support bounds (lanes 0-31) -----------
  if (tid < 32) {
    const bool is_y = (tid < 16);
    const int  i    = tid & 15;
    const float s1  = bbox[r * 5 + (is_y ? 2 : 1)] * SCALE_ - 0.5f;
    const float s2  = bbox[r * 5 + (is_y ? 4 : 3)] * SCALE_ - 0.5f;
    const float bin = (s2 - s1) * (1.0f / OUT_);
    const float v   = s1 + ((float)i + 0.5f) * (bin * 0.5f);
    const bool valid = (v >= -1.0f) && (v <= (float)H_);
    int lo = 64;
    if (valid) {
      float vc  = fminf(fmaxf(v, 0.0f), 31.0f);
      float lof = floorf(vc);
      float fr  = vc - lof;
      lo = (int)lof;
      int hi = min(lo + 1, 31);
      float* A = is_y ? sAy : sAx;
      atomicAdd(&A[lo], 1.0f - fr);
      atomicAdd(&A[hi], fr);
    }
    int mn = lo;
    #pragma unroll
    for (int m = 8; m >= 1; m >>= 1) mn = min(mn, __shfl_xor(mn, m, 16));
    mn = min(mn, 31);
    if (tid == 0)  { sb[0] = mn; sb[2] = (int)bbox[r * 5]; }
    if (tid == 16) { sb[1] = mn; }
  }
  __syncthreads();

  const int ylo = sb[0], xlo = sb[1], bidx = sb[2];

  // --- Phase B: gather over (yk, c-quad) tasks, fixed 9x9 support ---------
  for (int t = tid; t < 9 * 132; t += 256) {
    const int yk = t / 132;
    const int c4 = t - yk * 132;
    const float wy = sAy[ylo + yk];
    float4 rs = make_float4(0.f, 0.f, 0.f, 0.f);
    if (wy != 0.f) {   // rows beyond support: weight exactly 0, skip loads
      const float* rp =
          feat_t + ((size_t)bidx * HW_ + (ylo + yk) * W_ + xlo) * C_ + c4 * 4;
      #pragma unroll
      for (int k = 0; k < 9; ++k) {     // 9 independent loads in flight
        const float wx = sAx[xlo + k];  // zero beyond support
        const float4 v = *(const float4*)(rp + (size_t)k * C_);
        rs.x += wx * v.x; rs.y += wx * v.y;
        rs.z += wx * v.z; rs.w += wx * v.w;
      }
      rs.x *= wy; rs.y *= wy; rs.z *= wy; rs.w *= wy;
    }
    *(float4*)&pooledP[yk][c4 * 4] = rs;
  }
  __syncthreads();

  // --- reduce over Y, write pooled ----------------------------------------
  if (tid < 132) {
    float4 a = make_float4(0.f, 0.f, 0.f, 0.f);
    #pragma unroll
    for (int yk = 0; yk < 9; ++yk) {
      const float4 v = *(const float4*)&pooledP[yk][tid * 4];
      a.x += v.x; a.y += v.y; a.z += v.z; a.w += v.w;
    }
    const float s = 1.0f / 256.0f;
    a.x *= s; a.y *= s; a.z *= s; a.w *= s;
    *(float4*)&pooled_g[(size_t)r * C_ + tid * 4] = a;
  }
}

// ---------------------------------------------------------------------------
// Kernel 3: MLP for 8 rois per block (W1 column loaded once, used 8x).
// grid = 128, block = 256.
// ---------------------------------------------------------------------------
__global__ __launch_bounds__(256) void mlp8(
    const float* __restrict__ pooled_g,
    const float* __restrict__ W1, const float* __restrict__ b1,
    const float* __restrict__ W2, const float* __restrict__ b2,
    const float* __restrict__ W3, const float* __restrict__ b3,
    float* __restrict__ out) {
  const int rbase = blockIdx.x * 8;
  const int tid = threadIdx.x;

  __shared__ __align__(16) float sp[8][C_];   // 16.9 KB
  __shared__ float sh1[8][128];
  __shared__ float sh2[8][32];

  // load 8 pooled vectors
  for (int q = tid; q < 8 * 132; q += 256) {
    const int ri = q >> 7;          // q/128? no: use exact div by 132
    // recompute exactly:
    const int ri2 = q / 132;
    const int c4  = q - ri2 * 132;
    *(float4*)&sp[ri2][c4 * 4] =
        *(const float4*)&pooled_g[(size_t)(rbase + ri2) * C_ + c4 * 4];
    (void)ri;
  }
  __syncthreads();

  // --- Layer 1 (528 -> 128, relu): each thread = 1 output j x 4 rois ------
  {
    const int j   = tid & 127;
    const int ri0 = (tid >> 7) * 4;
    float a0 = 0.f, a1 = 0.f, a2 = 0.f, a3 = 0.f;
    const float* w = W1 + j;
    #pragma unroll 4
    for (int c = 0; c < C_; ++c) {
      const float wv = w[(size_t)c * 128];   // one load, 4 uses
      a0 += sp[ri0 + 0][c] * wv;             // LDS broadcast reads
      a1 += sp[ri0 + 1][c] * wv;
      a2 += sp[ri0 + 2][c] * wv;
      a3 += sp[ri0 + 3][c] * wv;
    }
    const float bb = b1[j];
    sh1[ri0 + 0][j] = fmaxf(a0 + bb, 0.f);
    sh1[ri0 + 1][j] = fmaxf(a1 + bb, 0.f);
    sh1[ri0 + 2][j] = fmaxf(a2 + bb, 0.f);
    sh1[ri0 + 3][j] = fmaxf(a3 + bb, 0.f);
  }
  __syncthreads();

  // --- Layer 2 (128 -> 32): thread = (roi, out j) --------------------------
  {
    const int j  = tid & 31;
    const int ri = tid >> 5;
    float acc = b2[j];
    #pragma unroll 4
    for (int k = 0; k < 128; ++k) {
      acc += sh1[ri][k] * W2[k * 32 + j];
    }
    sh2[ri][j] = acc;
  }
  __syncthreads();

  // --- Layer 3 (32 -> 1) + sigmoid: 32-lane group reduce per roi ----------
  {
    const int ri = tid >> 5;
    const int k  = tid & 31;
    float t = sh2[ri][k] * W3[k];
    #pragma unroll
    for (int off = 16; off >= 1; off >>= 1) t += __shfl_down(t, off, 32);
    if (k == 0) out[rbase + ri] = 1.0f / (1.0f + expf(-(t + b3[0])));
  }
}

extern "C" void kernel_launch(void* const* d_in, const int* in_sizes, int n_in,
                              void* d_out, int out_size, void* d_ws, size_t ws_size,
                              hipStream_t stream) {
  const float* x    = (const float*)d_in[0];
  const float* bbox = (const float*)d_in[1];
  const float* W1   = (const float*)d_in[2];
  const float* b1   = (const float*)d_in[3];
  const float* W2   = (const float*)d_in[4];
  const float* b2   = (const float*)d_in[5];
  const float* W3   = (const float*)d_in[6];
  const float* b3   = (const float*)d_in[7];
  float* out = (float*)d_out;

  float* feat_t = (float*)d_ws;                       // 17,301,504 B
  float* pooled = (float*)((char*)d_ws + 17301504);   // 1024*528*4 = 2.16 MB

  mean_transpose<<<dim3(16, 9, 8), 256, 0, stream>>>(x, feat_t);
  roi_pool<<<R_, 256, 0, stream>>>(feat_t, bbox, pooled);
  mlp8<<<R_ / 8, 256, 0, stream>>>(pooled, W1, b1, W2, b2, W3, b3, out);
}